// Round 1
// baseline (9291.036 us; speedup 1.0000x reference)
//
#include <hip/hip_runtime.h>
#include <hip/hip_cooperative_groups.h>

namespace cg = cooperative_groups;

// Problem geometry
#define N_ROWS 8192   // 4*2048 latents
#define N_COLS 2048   // codebook entries
#define NBLK   256    // cooperative grid blocks
#define TPB    1024   // threads per block (16 waves)

// ---------------------------------------------------------------------------
// fast f64 exp, |x| <= ~102, rel err ~2e-16 (Cody-Waite + Taylor-13)
// ---------------------------------------------------------------------------
__device__ __forceinline__ double fexp(double x) {
  const double L2E   = 1.4426950408889634074;
  const double LN2HI = 6.93147180369123816490e-01;  // 33 significant bits
  const double LN2LO = 1.90821492927058770002e-10;
  double t = x * L2E;
  double n = rint(t);
  double r = __fma_rn(n, -LN2HI, x);
  r = __fma_rn(n, -LN2LO, r);
  double p = 1.6059043836821613e-10;                // 1/13!
  p = __fma_rn(p, r, 2.08767569878681e-09);
  p = __fma_rn(p, r, 2.505210838544172e-08);
  p = __fma_rn(p, r, 2.7557319223985893e-07);
  p = __fma_rn(p, r, 2.755731922398589e-06);
  p = __fma_rn(p, r, 2.48015873015873e-05);
  p = __fma_rn(p, r, 1.9841269841269841e-04);
  p = __fma_rn(p, r, 1.3888888888888889e-03);
  p = __fma_rn(p, r, 8.333333333333333e-03);
  p = __fma_rn(p, r, 4.1666666666666664e-02);
  p = __fma_rn(p, r, 1.6666666666666666e-01);
  p = __fma_rn(p, r, 0.5);
  p = __fma_rn(p, r, 1.0);
  p = __fma_rn(p, r, 1.0);
  long long ni = (long long)n;                      // |n| <= ~147 -> normal range
  double sc = __longlong_as_double((ni + 1023LL) << 52);
  return p * sc;
}

// ---------------------------------------------------------------------------
// per-row squared norms (wave per row, 128 cols)
// ---------------------------------------------------------------------------
__global__ void rowsq_kernel(const float* __restrict__ p, float* __restrict__ o, int nrows) {
  int w = (int)((blockIdx.x * blockDim.x + threadIdx.x) >> 6);
  int lane = threadIdx.x & 63;
  if (w >= nrows) return;
  float2 v = ((const float2*)(p + (size_t)w * 128))[lane];
  float s = v.x * v.x + v.y * v.y;
  #pragma unroll
  for (int off = 32; off; off >>= 1) s += __shfl_down(s, off);
  if (lane == 0) o[w] = s;
}

// ---------------------------------------------------------------------------
// d[i,k] = xx[i] + cc[k] - 2*x.c  (64x64 tile, K=128), + per-block min/max
// ---------------------------------------------------------------------------
__global__ __launch_bounds__(256) void dist_kernel(
    const float* __restrict__ x, const float* __restrict__ cb,
    const float* __restrict__ xx, const float* __restrict__ cc,
    float* __restrict__ dbuf, float* __restrict__ minp, float* __restrict__ maxp)
{
  __shared__ float xs[64][129];
  __shared__ float csh[64][129];
  const int bi = blockIdx.y;   // row tile (of 128)
  const int bk = blockIdx.x;   // col tile (of 32)
  const int t  = threadIdx.x;

  const float4* xg = (const float4*)(x  + (size_t)bi * 64 * 128);
  const float4* cg4 = (const float4*)(cb + (size_t)bk * 64 * 128);
  #pragma unroll
  for (int i = 0; i < 8; ++i) {
    int e = t + i * 256;       // float4 index 0..2047
    int r = e >> 5, c = e & 31;
    float4 v = xg[e];
    xs[r][4*c+0] = v.x; xs[r][4*c+1] = v.y; xs[r][4*c+2] = v.z; xs[r][4*c+3] = v.w;
    float4 w = cg4[e];
    csh[r][4*c+0] = w.x; csh[r][4*c+1] = w.y; csh[r][4*c+2] = w.z; csh[r][4*c+3] = w.w;
  }
  __syncthreads();

  const int rg = t >> 4, cgi = t & 15;
  float acc[4][4];
  #pragma unroll
  for (int i = 0; i < 4; ++i)
    #pragma unroll
    for (int j = 0; j < 4; ++j) acc[i][j] = 0.f;

  for (int k = 0; k < 128; ++k) {
    float a0 = xs[rg*4+0][k], a1 = xs[rg*4+1][k], a2 = xs[rg*4+2][k], a3 = xs[rg*4+3][k];
    float b0 = csh[cgi*4+0][k], b1 = csh[cgi*4+1][k], b2 = csh[cgi*4+2][k], b3 = csh[cgi*4+3][k];
    acc[0][0] += a0*b0; acc[0][1] += a0*b1; acc[0][2] += a0*b2; acc[0][3] += a0*b3;
    acc[1][0] += a1*b0; acc[1][1] += a1*b1; acc[1][2] += a1*b2; acc[1][3] += a1*b3;
    acc[2][0] += a2*b0; acc[2][1] += a2*b1; acc[2][2] += a2*b2; acc[2][3] += a2*b3;
    acc[3][0] += a3*b0; acc[3][1] += a3*b1; acc[3][2] += a3*b2; acc[3][3] += a3*b3;
  }

  float lmin = 1e30f, lmax = -1e30f;
  #pragma unroll
  for (int i = 0; i < 4; ++i) {
    int gi = bi*64 + rg*4 + i;
    float xxv = xx[gi];
    float dv[4];
    #pragma unroll
    for (int j = 0; j < 4; ++j) {
      int gk = bk*64 + cgi*4 + j;
      dv[j] = (xxv + cc[gk]) - 2.f * acc[i][j];
      lmin = fminf(lmin, dv[j]); lmax = fmaxf(lmax, dv[j]);
    }
    float4 o = make_float4(dv[0], dv[1], dv[2], dv[3]);
    *((float4*)(dbuf + (size_t)gi * N_COLS + bk*64 + cgi*4)) = o;
  }

  // block min/max
  #pragma unroll
  for (int off = 32; off; off >>= 1) {
    lmin = fminf(lmin, __shfl_down(lmin, off));
    lmax = fmaxf(lmax, __shfl_down(lmax, off));
  }
  __shared__ float rmn[4], rmx[4];
  int wave = t >> 6, lane = t & 63;
  if (lane == 0) { rmn[wave] = lmin; rmx[wave] = lmax; }
  __syncthreads();
  if (t == 0) {
    float mn = fminf(fminf(rmn[0], rmn[1]), fminf(rmn[2], rmn[3]));
    float mx = fmaxf(fmaxf(rmx[0], rmx[1]), fmaxf(rmx[2], rmx[3]));
    int bid = bi * gridDim.x + bk;
    minp[bid] = mn; maxp[bid] = mx;
  }
}

// ---------------------------------------------------------------------------
// reduce 4096 min/max partials -> mid, amp (f32, exactly like reference)
// ---------------------------------------------------------------------------
__global__ __launch_bounds__(1024) void minmax_reduce_kernel(
    const float* __restrict__ minp, const float* __restrict__ maxp, float* __restrict__ sc)
{
  int t = threadIdx.x;
  float mn = 1e30f, mx = -1e30f;
  for (int i = t; i < 4096; i += 1024) { mn = fminf(mn, minp[i]); mx = fmaxf(mx, maxp[i]); }
  #pragma unroll
  for (int off = 32; off; off >>= 1) {
    mn = fminf(mn, __shfl_down(mn, off));
    mx = fmaxf(mx, __shfl_down(mx, off));
  }
  __shared__ float smn[16], smx[16];
  int wave = t >> 6, lane = t & 63;
  if (lane == 0) { smn[wave] = mn; smx[wave] = mx; }
  __syncthreads();
  if (t == 0) {
    for (int w = 1; w < 16; ++w) { mn = fminf(mn, smn[w]); mx = fmaxf(mx, smx[w]); }
    float mid = (mx + mn) * 0.5f;
    float amp = mx - mid + 1e-5f;
    sc[0] = mid; sc[1] = amp;
  }
}

// ---------------------------------------------------------------------------
// center in place: dc = (d - mid) / amp, rounded to f32 (matches reference)
// ---------------------------------------------------------------------------
__global__ void center_kernel(float* __restrict__ dbuf, const float* __restrict__ sc) {
  float mid = sc[0], amp = sc[1];
  size_t stride = (size_t)gridDim.x * blockDim.x;
  for (size_t i = blockIdx.x * blockDim.x + threadIdx.x; i < (size_t)N_ROWS * N_COLS; i += stride) {
    float dv = dbuf[i];
    dbuf[i] = (dv - mid) / amp;   // IEEE f32 div (no fast-math)
  }
}

// ---------------------------------------------------------------------------
// cooperative Sinkhorn: 100 x { colsum -> v ; rowsum -> u }, then argmax,
// gather x_q, straight-through output, loss.
// Scaling-vector form: v = 1/(K * E^T u), u = 1/(N * E v); E = exp(-dc/0.01).
// ---------------------------------------------------------------------------
__global__ __launch_bounds__(TPB) void sinkhorn_kernel(
    const float* __restrict__ dc, double* __restrict__ part,
    double* __restrict__ vg, double* __restrict__ lossp,
    const float* __restrict__ x, const float* __restrict__ cb,
    float* __restrict__ out)
{
  cg::grid_group grid = cg::this_grid();
  __shared__ double sh[2048];
  __shared__ double u_loc[32];
  __shared__ int idx_loc[32];
  const int b = blockIdx.x, t = threadIdx.x;
  const int lane = t & 63, wave = t >> 6;
  const int row0 = b * 32;                    // 32 rows per block
  const double C = -1.0 / 0.01;

  if (t < 32) u_loc[t] = 1.0;
  __syncthreads();

  for (int it = 0; it < 100; ++it) {
    // ---- pass C: partial column sums of u_i * E[i,k] for my 32 rows
    double a0 = 0.0, a1 = 0.0;
    for (int r = 0; r < 32; ++r) {
      double u = u_loc[r];
      const float* rp = dc + ((size_t)(row0 + r) << 11);
      a0 += u * fexp((double)rp[t] * C);
      a1 += u * fexp((double)rp[t + 1024] * C);
    }
    part[((size_t)b << 11) + t] = a0;
    part[((size_t)b << 11) + t + 1024] = a1;
    grid.sync();

    // ---- reduce 256 partials for my 8 columns -> v_k = 1/(K * cs_k)
    {
      int kk = t & 7, p = t >> 3;             // p in 0..127
      int col = (b << 3) + kk;
      double s = part[((size_t)p << 11) + col] + part[((size_t)(p + 128) << 11) + col];
      sh[(kk << 7) + p] = s;
      __syncthreads();
      for (int off = 64; off >= 1; off >>= 1) {
        if (p < off) sh[(kk << 7) + p] += sh[(kk << 7) + p + off];
        __syncthreads();
      }
      if (t < 8) vg[(b << 3) + t] = 1.0 / (2048.0 * sh[t << 7]);
    }
    grid.sync();

    // ---- pass R: row sums of v_k * E[i,k]; u_i = 1/(N * rs_i)
    for (int i = t; i < 2048; i += TPB) sh[i] = vg[i];
    __syncthreads();
    #pragma unroll
    for (int rr = 0; rr < 2; ++rr) {
      int r = wave + (rr << 4);
      const float* rp = dc + ((size_t)(row0 + r) << 11);
      double s = 0.0;
      for (int j = 0; j < 32; ++j) {
        int k = lane + (j << 6);
        s += sh[k] * fexp((double)rp[k] * C);
      }
      #pragma unroll
      for (int off = 32; off; off >>= 1) s += __shfl_down(s, off);
      if (lane == 0) u_loc[r] = 1.0 / (8192.0 * s);
    }
    __syncthreads();
  }

  // ---- argmax_k v_k * E[i,k]  (sh still holds v; first-occurrence ties)
  #pragma unroll
  for (int rr = 0; rr < 2; ++rr) {
    int r = wave + (rr << 4);
    const float* rp = dc + ((size_t)(row0 + r) << 11);
    double bv = -1.0; int bk = 0;
    for (int j = 0; j < 32; ++j) {
      int k = lane + (j << 6);
      double val = sh[k] * fexp((double)rp[k] * C);
      if (val > bv) { bv = val; bk = k; }
    }
    #pragma unroll
    for (int off = 32; off; off >>= 1) {
      double ov = __shfl_down(bv, off);
      int ok = __shfl_down(bk, off);
      if (ov > bv || (ov == bv && ok < bk)) { bv = ov; bk = ok; }
    }
    if (lane == 0) {
      idx_loc[r] = bk;
      out[1048577 + row0 + r] = (float)bk;   // indices output (as f32)
    }
  }
  __syncthreads();

  // ---- gather x_q, straight-through out, loss partial
  double lsum = 0.0;
  #pragma unroll
  for (int c = 0; c < 4; ++c) {
    int e = (c << 10) + t;                   // 0..4095 = 32 rows x 128
    int r = e >> 7, d = e & 127;
    int k = idx_loc[r];
    float cv = cb[(k << 7) + d];
    size_t gi = (((size_t)(row0 + r)) << 7) + d;
    float xv = x[gi];
    float diff = cv - xv;                    // f32, as reference
    out[gi] = xv + diff;                     // x + (x_q - x)
    lsum += (double)diff * (double)diff;
  }
  #pragma unroll
  for (int off = 32; off; off >>= 1) lsum += __shfl_down(lsum, off);
  __syncthreads();                           // reuse sh
  if (lane == 0) sh[wave] = lsum;
  __syncthreads();
  if (t == 0) {
    double s = 0.0;
    for (int w = 0; w < 16; ++w) s += sh[w];
    lossp[b] = s;
  }
  grid.sync();
  if (b == 0 && t == 0) {
    double s = 0.0;
    for (int i = 0; i < NBLK; ++i) s += lossp[i];
    double L = s / 1048576.0;
    out[1048576] = (float)(0.2 * L + 0.8 * L);
  }
}

// ---------------------------------------------------------------------------
extern "C" void kernel_launch(void* const* d_in, const int* in_sizes, int n_in,
                              void* d_out, int out_size, void* d_ws, size_t ws_size,
                              hipStream_t stream) {
  const float* x  = (const float*)d_in[0];   // [4,2048,128]
  const float* cb = (const float*)d_in[1];   // [2048,128]
  float* out = (float*)d_out;                // [1048576 xq | 1 loss | 8192 idx]
  char* ws = (char*)d_ws;

  float*  dcbuf = (float*) (ws);                       // 67108864 B
  double* part  = (double*)(ws + 67108864);            //  4194304 B
  double* vgv   = (double*)(ws + 71303168);            //    16384 B
  double* lossp = (double*)(ws + 71319552);            //     2048 B
  float*  xx    = (float*) (ws + 71321600);            //    32768 B
  float*  cc    = (float*) (ws + 71354368);            //     8192 B
  float*  minp  = (float*) (ws + 71362560);            //    16384 B
  float*  maxp  = (float*) (ws + 71378944);            //    16384 B
  float*  scp   = (float*) (ws + 71395328);            //       16 B

  rowsq_kernel<<<2048, 256, 0, stream>>>(x, xx, N_ROWS);
  rowsq_kernel<<<512, 256, 0, stream>>>(cb, cc, N_COLS);
  dim3 dg(32, 128);
  dist_kernel<<<dg, 256, 0, stream>>>(x, cb, xx, cc, dcbuf, minp, maxp);
  minmax_reduce_kernel<<<1, 1024, 0, stream>>>(minp, maxp, scp);
  center_kernel<<<2048, 256, 0, stream>>>(dcbuf, scp);

  void* args[] = {(void*)&dcbuf, (void*)&part, (void*)&vgv, (void*)&lossp,
                  (void*)&x, (void*)&cb, (void*)&out};
  hipLaunchCooperativeKernel((void*)sinkhorn_kernel, dim3(NBLK), dim3(TPB),
                             args, 0, stream);
}